// Round 8
// baseline (129.154 us; speedup 1.0000x reference)
//
#include <hip/hip_runtime.h>

#define BATCH 128
#define SENS 128
#define UNITS 512
#define MOTOR 64
#define UNFOLDS 6
#define L2E 1.442695040888963f
#define EPS 1e-8f

#define BT 8      // batches per block (register-blocked)
#define UT 8      // units per block
#define STP 12    // transposed LDS row stride (8 data + 4 pad, conflict-free)
#define THR 512   // threads per block: 8 waves -> 32 waves/CU at 4 blocks/CU

// ===========================================================================
// First unfold: fuses x-affine + sensory accumulators (written to wns/wds),
// on-the-fly weight fold (bt==0 blocks persist pw4 for later unfolds), and
// ODE unfold step 0.  1024 blocks x 512 threads.
// ===========================================================================
__global__ __launch_bounds__(THR, 8) void unfold_first_kernel(
    const float* __restrict__ inputs, const float* __restrict__ state,
    const float* __restrict__ sigma, const float* __restrict__ mu,
    const float* __restrict__ w, const float* __restrict__ erev,
    const float* __restrict__ mask,
    const float* __restrict__ ssig, const float* __restrict__ smu,
    const float* __restrict__ sw, const float* __restrict__ serev,
    const float* __restrict__ smask,
    const float* __restrict__ input_w, const float* __restrict__ input_b,
    const float* __restrict__ gleak, const float* __restrict__ vleak,
    const float* __restrict__ cm,
    float4* __restrict__ pw4,
    float* __restrict__ wns, float* __restrict__ wds,
    float* __restrict__ dst)
{
    __shared__ __align__(16) float stT[UNITS][STP];  // state transposed [v][b]
    __shared__ __align__(16) float xsT[SENS][STP];   // x transposed [s][b]
    __shared__ float2 red[8][BT][UT];

    int tid = threadIdx.x;

    // block tile mapping (bijective XCD chunking: 1024 % 8 == 0)
    int logical = (blockIdx.x & 7) * 128 + (blockIdx.x >> 3);
    int ut = logical >> 4;                 // 0..63
    int bt = logical & 15;                 // 0..15
    int b0 = bt * BT;
    int u0 = ut * UT;

    int ul  = tid & 7;
    int grp = tid >> 3;                    // 0..63
    int u = u0 + ul;
    int lane = tid & 63;
    int wid = tid >> 6;                    // 0..7

    // ---- stage state tile (transposed) and x tile (affine applied) ----
    {
        int bl = tid & 7;
        int v4b = tid >> 3;                // 0..63
        const float4* sv = (const float4*)(state + (size_t)b0 * UNITS);
        #pragma unroll
        for (int k = 0; k < 2; ++k) {
            int v4 = v4b + 64 * k;         // 0..127
            float4 t4 = sv[bl * (UNITS / 4) + v4];
            stT[v4 * 4 + 0][bl] = t4.x;
            stT[v4 * 4 + 1][bl] = t4.y;
            stT[v4 * 4 + 2][bl] = t4.z;
            stT[v4 * 4 + 3][bl] = t4.w;
        }
        if (v4b < 32) {                    // x: 8 rows x 32 float4
            const float4* xv = (const float4*)(inputs + (size_t)(b0 + bl) * SENS);
            float4 t4 = xv[v4b];
            float4 iw = ((const float4*)input_w)[v4b];
            float4 ib = ((const float4*)input_b)[v4b];
            xsT[v4b * 4 + 0][bl] = __builtin_fmaf(t4.x, iw.x, ib.x);
            xsT[v4b * 4 + 1][bl] = __builtin_fmaf(t4.y, iw.y, ib.y);
            xsT[v4b * 4 + 2][bl] = __builtin_fmaf(t4.z, iw.z, ib.z);
            xsT[v4b * 4 + 3][bl] = __builtin_fmaf(t4.w, iw.w, ib.w);
        }
    }
    __syncthreads();

    // ---- sensory accumulators (raw weights, used once) ----
    float num[BT], den[BT];
    #pragma unroll
    for (int b = 0; b < BT; ++b) { num[b] = 0.f; den[b] = 0.f; }

    #pragma unroll
    for (int i = 0; i < SENS / 64; ++i) {  // s = grp + 64*i
        int s = grp + 64 * i;
        size_t k = (size_t)s * UNITS + u;
        float sgv = ssig[k] * L2E;
        float mt  = smu[k] * sgv;
        float wmv = sw[k] * smask[k];
        float wev = wmv * serev[k];
        const float4* sp = (const float4*)&xsT[s][0];
        float4 xa = sp[0];
        float4 xb = sp[1];
        float sarr[8] = {xa.x, xa.y, xa.z, xa.w, xb.x, xb.y, xb.z, xb.w};
        #pragma unroll
        for (int b = 0; b < BT; ++b) {
            float t = __builtin_fmaf(-sarr[b], sgv, mt);
            float e = __builtin_amdgcn_exp2f(t);
            float sg = __builtin_amdgcn_rcpf(1.0f + e);
            num[b] = __builtin_fmaf(wev, sg, num[b]);
            den[b] = __builtin_fmaf(wmv, sg, den[b]);
        }
    }
    #pragma unroll
    for (int b = 0; b < BT; ++b) {
        #pragma unroll
        for (int m = 8; m <= 32; m <<= 1) {
            num[b] += __shfl_xor(num[b], m, 64);
            den[b] += __shfl_xor(den[b], m, 64);
        }
    }
    if (lane < 8) {
        #pragma unroll
        for (int b = 0; b < BT; ++b)
            red[wid][b][lane] = make_float2(num[b], den[b]);
    }
    __syncthreads();
    float esn = 0.f, esd = 0.f;            // sensory sums (valid for tid<64)
    if (tid < 64) {
        int uu = tid & 7;
        int bb = tid >> 3;
        #pragma unroll
        for (int k = 0; k < 8; ++k) {
            float2 v = red[k][bb][uu];
            esn += v.x; esd += v.y;
        }
        int gidx = (b0 + bb) * UNITS + (u0 + uu);
        wns[gidx] = esn;                   // persist for unfolds 1..5
        wds[gidx] = esd;
    }
    __syncthreads();                       // red[] reused below

    // ---- recurrent accumulation, fold-on-the-fly; bt==0 persists pw4 ----
    #pragma unroll
    for (int b = 0; b < BT; ++b) { num[b] = 0.f; den[b] = 0.f; }

    #pragma unroll 4
    for (int i = 0; i < UNITS / 64; ++i) { // v = grp + 64*i
        int v = grp + 64 * i;
        size_t k = (size_t)v * UNITS + u;
        float sgv = sigma[k] * L2E;
        float wmv = w[k] * mask[k];
        float4 q;
        q.x = sgv; q.y = mu[k] * sgv; q.z = wmv; q.w = wmv * erev[k];
        if (bt == 0) pw4[k] = q;
        const float4* sp = (const float4*)&stT[v][0];
        float4 xa = sp[0];
        float4 xb = sp[1];
        float sarr[8] = {xa.x, xa.y, xa.z, xa.w, xb.x, xb.y, xb.z, xb.w};
        #pragma unroll
        for (int b = 0; b < BT; ++b) {
            float t = __builtin_fmaf(-sarr[b], q.x, q.y);
            float e = __builtin_amdgcn_exp2f(t);
            float sg = __builtin_amdgcn_rcpf(1.0f + e);
            num[b] = __builtin_fmaf(q.w, sg, num[b]);
            den[b] = __builtin_fmaf(q.z, sg, den[b]);
        }
    }
    #pragma unroll
    for (int b = 0; b < BT; ++b) {
        #pragma unroll
        for (int m = 8; m <= 32; m <<= 1) {
            num[b] += __shfl_xor(num[b], m, 64);
            den[b] += __shfl_xor(den[b], m, 64);
        }
    }
    if (lane < 8) {
        #pragma unroll
        for (int b = 0; b < BT; ++b)
            red[wid][b][lane] = make_float2(num[b], den[b]);
    }
    __syncthreads();
    if (tid < 64) {
        int uu = tid & 7;
        int bb = tid >> 3;
        float n = 0.f, d = 0.f;
        #pragma unroll
        for (int k = 0; k < 8; ++k) {
            float2 v = red[k][bb][uu];
            n += v.x; d += v.y;
        }
        int gu = u0 + uu;
        int gb = b0 + bb;
        float vpre = stT[gu][bb];
        float g = gleak[gu];
        float c = cm[gu] * (float)UNFOLDS;
        float numer = __builtin_fmaf(c, vpre,
                        __builtin_fmaf(g, vleak[gu], esn + n));
        float denom = c + g + esd + d + EPS;
        dst[gb * UNITS + gu] = numer * __builtin_amdgcn_rcpf(denom);
    }
}

// ===========================================================================
// Unfolds 1..5: packed float4 weights, transposed LDS state, 8 batch-
// accumulators per thread, shfl + LDS reduce.  512 thr -> 32 waves/CU.
// ===========================================================================
__global__ __launch_bounds__(THR, 8) void unfold_kernel(
    const float* __restrict__ src,
    float* __restrict__ dst,
    const float4* __restrict__ pw4,
    const float* __restrict__ wns, const float* __restrict__ wds,
    const float* __restrict__ gleak, const float* __restrict__ vleak,
    const float* __restrict__ cm,
    const float* __restrict__ output_w, const float* __restrict__ output_b,
    float* __restrict__ out_motor,
    int last)
{
    __shared__ __align__(16) float stT[UNITS][STP];
    __shared__ float2 red[8][BT][UT];

    int phys = blockIdx.x;
    int logical = (phys & 7) * 128 + (phys >> 3);
    int ut = logical >> 4;
    int bt = logical & 15;
    int b0 = bt * BT;
    int u0 = ut * UT;
    int tid = threadIdx.x;

    {
        const float4* sv = (const float4*)(src + (size_t)b0 * UNITS);
        int bl = tid & 7;
        int v4b = tid >> 3;                // 0..63
        #pragma unroll
        for (int k = 0; k < 2; ++k) {
            int v4 = v4b + 64 * k;
            float4 t = sv[bl * (UNITS / 4) + v4];
            stT[v4 * 4 + 0][bl] = t.x;
            stT[v4 * 4 + 1][bl] = t.y;
            stT[v4 * 4 + 2][bl] = t.z;
            stT[v4 * 4 + 3][bl] = t.w;
        }
    }
    __syncthreads();

    int ul = tid & 7;
    int vs = tid >> 3;                     // 0..63
    int u = u0 + ul;

    float num[BT], den[BT];
    #pragma unroll
    for (int b = 0; b < BT; ++b) { num[b] = 0.f; den[b] = 0.f; }

    const float4* pv = pw4 + (size_t)vs * UNITS + u;
    const float* srow = &stT[vs][0];
    #pragma unroll 4
    for (int i = 0; i < UNITS / 64; ++i) { // v = vs + 64*i
        float4 q = pv[0];
        pv += 64 * UNITS;
        const float4* sp = (const float4*)srow;
        float4 xa = sp[0];
        float4 xb = sp[1];
        srow += 64 * STP;
        float sarr[8] = {xa.x, xa.y, xa.z, xa.w, xb.x, xb.y, xb.z, xb.w};
        #pragma unroll
        for (int b = 0; b < BT; ++b) {
            float t = __builtin_fmaf(-sarr[b], q.x, q.y);
            float e = __builtin_amdgcn_exp2f(t);
            float sg = __builtin_amdgcn_rcpf(1.0f + e);
            num[b] = __builtin_fmaf(q.w, sg, num[b]);
            den[b] = __builtin_fmaf(q.z, sg, den[b]);
        }
    }
    #pragma unroll
    for (int b = 0; b < BT; ++b) {
        #pragma unroll
        for (int m = 8; m <= 32; m <<= 1) {
            num[b] += __shfl_xor(num[b], m, 64);
            den[b] += __shfl_xor(den[b], m, 64);
        }
    }
    int lane = tid & 63;
    int wid = tid >> 6;                    // 0..7
    if (lane < 8) {
        #pragma unroll
        for (int b = 0; b < BT; ++b)
            red[wid][b][lane] = make_float2(num[b], den[b]);
    }
    __syncthreads();
    if (tid < 64) {
        int uu = tid & 7;
        int bb = tid >> 3;
        float n = 0.f, d = 0.f;
        #pragma unroll
        for (int k = 0; k < 8; ++k) {
            float2 v = red[k][bb][uu];
            n += v.x; d += v.y;
        }
        int gu = u0 + uu;
        int gb = b0 + bb;
        float vpre = stT[gu][bb];
        float g = gleak[gu];
        float c = cm[gu] * (float)UNFOLDS;
        int gidx = gb * UNITS + gu;
        float numer = __builtin_fmaf(c, vpre,
                        __builtin_fmaf(g, vleak[gu], wns[gidx] + n));
        float denom = c + g + wds[gidx] + d + EPS;
        float res = numer * __builtin_amdgcn_rcpf(denom);
        dst[gidx] = res;
        if (last && gu < MOTOR) {
            out_motor[gb * MOTOR + gu] =
                __builtin_fmaf(res, output_w[gu], output_b[gu]);
        }
    }
}

// ===========================================================================
extern "C" void kernel_launch(void* const* d_in, const int* in_sizes, int n_in,
                              void* d_out, int out_size, void* d_ws, size_t ws_size,
                              hipStream_t stream) {
    const float* inputs   = (const float*)d_in[0];
    const float* state    = (const float*)d_in[1];
    const float* gleak    = (const float*)d_in[2];
    const float* vleak    = (const float*)d_in[3];
    const float* cm       = (const float*)d_in[4];
    const float* sigma    = (const float*)d_in[5];
    const float* mu       = (const float*)d_in[6];
    const float* w        = (const float*)d_in[7];
    const float* erev     = (const float*)d_in[8];
    const float* ssig     = (const float*)d_in[9];
    const float* smu      = (const float*)d_in[10];
    const float* sw       = (const float*)d_in[11];
    const float* serev    = (const float*)d_in[12];
    const float* input_w  = (const float*)d_in[13];
    const float* input_b  = (const float*)d_in[14];
    const float* output_w = (const float*)d_in[15];
    const float* output_b = (const float*)d_in[16];
    const float* mask     = (const float*)d_in[17];
    const float* smask    = (const float*)d_in[18];

    float* out = (float*)d_out;
    float* ws  = (float*)d_ws;

    float4* pw4 = (float4*)ws;                 // U*U float4 (4 MB)
    float*  wns = ws + 4 * UNITS * UNITS;      // B*U
    float*  wds = wns + BATCH * UNITS;         // B*U
    float*  stA = wds + BATCH * UNITS;         // B*U
    float*  stB = stA + BATCH * UNITS;         // B*U

    // unfold 0: fused x-affine + sensory + fold + step
    unfold_first_kernel<<<1024, THR, 0, stream>>>(
        inputs, state, sigma, mu, w, erev, mask,
        ssig, smu, sw, serev, smask, input_w, input_b,
        gleak, vleak, cm, pw4, wns, wds, stA);

    // unfolds 1..5
    float* state_out = out + BATCH * MOTOR;
    float* dsts[5] = {stB, stA, stB, stA, state_out};
    const float* src = stA;
    for (int t = 0; t < 5; ++t) {
        int last = (t == 4) ? 1 : 0;
        unfold_kernel<<<1024, THR, 0, stream>>>(
            src, dsts[t], pw4, wns, wds,
            gleak, vleak, cm, output_w, output_b, out, last);
        src = dsts[t];
    }
}

// Round 9
// 80.655 us; speedup vs baseline: 1.6013x; 1.6013x over previous
//
#include <hip/hip_runtime.h>

#define BATCH 128
#define SENS 128
#define UNITS 512
#define MOTOR 64
#define UNFOLDS 6
#define L2E 1.442695040888963f
#define EPS 1e-8f

#define BT 8      // batches per block (register-blocked)
#define UT 8      // units per block
#define STP 12    // transposed LDS row stride (8 data + 4 pad, conflict-free)
#define THR 512   // unfold threads/block: 8 waves -> 32 waves/CU at 4 blocks/CU

// ===========================================================================
// Prep kernel (1024 x 256, reg-relaxed (256,4) -> no spill):
//  - fold recurrent weights: pw4[i] = {sig*l2e, mu*sig*l2e, w*m, w*m*erev},
//    one float4 per thread (1024*256 == UNITS*UNITS exactly).
//  - sensory accumulators from raw weights -> wns/wds  (8b x 8u tile,
//    8 batch-accumulators/thread, x affine applied during LDS staging).
// ===========================================================================
__global__ __launch_bounds__(256, 4) void prep_kernel(
    const float* __restrict__ inputs,
    const float* __restrict__ sigma, const float* __restrict__ mu,
    const float* __restrict__ w, const float* __restrict__ erev,
    const float* __restrict__ mask,
    const float* __restrict__ ssig, const float* __restrict__ smu,
    const float* __restrict__ sw, const float* __restrict__ serev,
    const float* __restrict__ smask,
    const float* __restrict__ input_w, const float* __restrict__ input_b,
    float4* __restrict__ pw4,
    float* __restrict__ wns, float* __restrict__ wds)
{
    __shared__ __align__(16) float xsT[SENS][STP];   // x transposed [s][b]
    __shared__ float2 red[4][BT][UT];

    int tid = threadIdx.x;

    // ---- fold recurrent weights (coalesced, exactly 1 float4/thread) ----
    {
        int i = blockIdx.x * 256 + tid;
        float sg = sigma[i] * L2E;
        float wmv = w[i] * mask[i];
        float4 q;
        q.x = sg; q.y = mu[i] * sg; q.z = wmv; q.w = wmv * erev[i];
        pw4[i] = q;
    }

    // block tile mapping (bijective XCD chunking: 1024 % 8 == 0)
    int logical = (blockIdx.x & 7) * 128 + (blockIdx.x >> 3);
    int ut = logical >> 4;                 // 0..63
    int bt = logical & 15;                 // 0..15
    int b0 = bt * BT;
    int u0 = ut * UT;

    int ul  = tid & 7;
    int grp = tid >> 3;                    // 0..31
    int u = u0 + ul;
    int lane = tid & 63;
    int wid = tid >> 6;                    // 0..3

    // ---- stage x tile transposed, affine applied ----
    {
        int bl = tid & 7;
        int s4 = tid >> 3;                 // 0..31
        const float4* xv = (const float4*)(inputs + (size_t)(b0 + bl) * SENS);
        float4 t4 = xv[s4];
        float4 iw = ((const float4*)input_w)[s4];
        float4 ib = ((const float4*)input_b)[s4];
        xsT[s4 * 4 + 0][bl] = __builtin_fmaf(t4.x, iw.x, ib.x);
        xsT[s4 * 4 + 1][bl] = __builtin_fmaf(t4.y, iw.y, ib.y);
        xsT[s4 * 4 + 2][bl] = __builtin_fmaf(t4.z, iw.z, ib.z);
        xsT[s4 * 4 + 3][bl] = __builtin_fmaf(t4.w, iw.w, ib.w);
    }
    __syncthreads();

    // ---- sensory accumulators (raw weights, used once) ----
    float num[BT], den[BT];
    #pragma unroll
    for (int b = 0; b < BT; ++b) { num[b] = 0.f; den[b] = 0.f; }

    #pragma unroll
    for (int i = 0; i < SENS / 32; ++i) {  // s = grp + 32*i
        int s = grp + 32 * i;
        size_t k = (size_t)s * UNITS + u;
        float sgv = ssig[k] * L2E;
        float mt  = smu[k] * sgv;
        float wmv = sw[k] * smask[k];
        float wev = wmv * serev[k];
        const float4* sp = (const float4*)&xsT[s][0];
        float4 xa = sp[0];
        float4 xb = sp[1];
        float sarr[8] = {xa.x, xa.y, xa.z, xa.w, xb.x, xb.y, xb.z, xb.w};
        #pragma unroll
        for (int b = 0; b < BT; ++b) {
            float t = __builtin_fmaf(-sarr[b], sgv, mt);
            float e = __builtin_amdgcn_exp2f(t);
            float sg = __builtin_amdgcn_rcpf(1.0f + e);
            num[b] = __builtin_fmaf(wev, sg, num[b]);
            den[b] = __builtin_fmaf(wmv, sg, den[b]);
        }
    }
    #pragma unroll
    for (int b = 0; b < BT; ++b) {
        #pragma unroll
        for (int m = 8; m <= 32; m <<= 1) {
            num[b] += __shfl_xor(num[b], m, 64);
            den[b] += __shfl_xor(den[b], m, 64);
        }
    }
    if (lane < 8) {
        #pragma unroll
        for (int b = 0; b < BT; ++b)
            red[wid][b][lane] = make_float2(num[b], den[b]);
    }
    __syncthreads();
    if (tid < 64) {
        int uu = tid & 7;
        int bb = tid >> 3;
        float n = 0.f, d = 0.f;
        #pragma unroll
        for (int k = 0; k < 4; ++k) {
            float2 v = red[k][bb][uu];
            n += v.x; d += v.y;
        }
        int gidx = (b0 + bb) * UNITS + (u0 + uu);
        wns[gidx] = n;
        wds[gidx] = d;
    }
}

// ===========================================================================
// Unfold (x6): packed float4 weights, transposed LDS state, 8 batch-
// accumulators per thread, shfl + LDS reduce.  512 thr -> 32 waves/CU.
// (R8-proven ~5 us config.)
// ===========================================================================
__global__ __launch_bounds__(THR, 8) void unfold_kernel(
    const float* __restrict__ src,
    float* __restrict__ dst,
    const float4* __restrict__ pw4,
    const float* __restrict__ wns, const float* __restrict__ wds,
    const float* __restrict__ gleak, const float* __restrict__ vleak,
    const float* __restrict__ cm,
    const float* __restrict__ output_w, const float* __restrict__ output_b,
    float* __restrict__ out_motor,
    int last)
{
    __shared__ __align__(16) float stT[UNITS][STP];
    __shared__ float2 red[8][BT][UT];

    int phys = blockIdx.x;
    int logical = (phys & 7) * 128 + (phys >> 3);
    int ut = logical >> 4;
    int bt = logical & 15;
    int b0 = bt * BT;
    int u0 = ut * UT;
    int tid = threadIdx.x;

    {
        const float4* sv = (const float4*)(src + (size_t)b0 * UNITS);
        int bl = tid & 7;
        int v4b = tid >> 3;                // 0..63
        #pragma unroll
        for (int k = 0; k < 2; ++k) {
            int v4 = v4b + 64 * k;
            float4 t = sv[bl * (UNITS / 4) + v4];
            stT[v4 * 4 + 0][bl] = t.x;
            stT[v4 * 4 + 1][bl] = t.y;
            stT[v4 * 4 + 2][bl] = t.z;
            stT[v4 * 4 + 3][bl] = t.w;
        }
    }
    __syncthreads();

    int ul = tid & 7;
    int vs = tid >> 3;                     // 0..63
    int u = u0 + ul;

    float num[BT], den[BT];
    #pragma unroll
    for (int b = 0; b < BT; ++b) { num[b] = 0.f; den[b] = 0.f; }

    const float4* pv = pw4 + (size_t)vs * UNITS + u;
    const float* srow = &stT[vs][0];
    #pragma unroll 4
    for (int i = 0; i < UNITS / 64; ++i) { // v = vs + 64*i
        float4 q = pv[0];
        pv += 64 * UNITS;
        const float4* sp = (const float4*)srow;
        float4 xa = sp[0];
        float4 xb = sp[1];
        srow += 64 * STP;
        float sarr[8] = {xa.x, xa.y, xa.z, xa.w, xb.x, xb.y, xb.z, xb.w};
        #pragma unroll
        for (int b = 0; b < BT; ++b) {
            float t = __builtin_fmaf(-sarr[b], q.x, q.y);
            float e = __builtin_amdgcn_exp2f(t);
            float sg = __builtin_amdgcn_rcpf(1.0f + e);
            num[b] = __builtin_fmaf(q.w, sg, num[b]);
            den[b] = __builtin_fmaf(q.z, sg, den[b]);
        }
    }
    #pragma unroll
    for (int b = 0; b < BT; ++b) {
        #pragma unroll
        for (int m = 8; m <= 32; m <<= 1) {
            num[b] += __shfl_xor(num[b], m, 64);
            den[b] += __shfl_xor(den[b], m, 64);
        }
    }
    int lane = tid & 63;
    int wid = tid >> 6;                    // 0..7
    if (lane < 8) {
        #pragma unroll
        for (int b = 0; b < BT; ++b)
            red[wid][b][lane] = make_float2(num[b], den[b]);
    }
    __syncthreads();
    if (tid < 64) {
        int uu = tid & 7;
        int bb = tid >> 3;
        float n = 0.f, d = 0.f;
        #pragma unroll
        for (int k = 0; k < 8; ++k) {
            float2 v = red[k][bb][uu];
            n += v.x; d += v.y;
        }
        int gu = u0 + uu;
        int gb = b0 + bb;
        float vpre = stT[gu][bb];
        float g = gleak[gu];
        float c = cm[gu] * (float)UNFOLDS;
        int gidx = gb * UNITS + gu;
        float numer = __builtin_fmaf(c, vpre,
                        __builtin_fmaf(g, vleak[gu], wns[gidx] + n));
        float denom = c + g + wds[gidx] + d + EPS;
        float res = numer * __builtin_amdgcn_rcpf(denom);
        dst[gidx] = res;
        if (last && gu < MOTOR) {
            out_motor[gb * MOTOR + gu] =
                __builtin_fmaf(res, output_w[gu], output_b[gu]);
        }
    }
}

// ===========================================================================
extern "C" void kernel_launch(void* const* d_in, const int* in_sizes, int n_in,
                              void* d_out, int out_size, void* d_ws, size_t ws_size,
                              hipStream_t stream) {
    const float* inputs   = (const float*)d_in[0];
    const float* state    = (const float*)d_in[1];
    const float* gleak    = (const float*)d_in[2];
    const float* vleak    = (const float*)d_in[3];
    const float* cm       = (const float*)d_in[4];
    const float* sigma    = (const float*)d_in[5];
    const float* mu       = (const float*)d_in[6];
    const float* w        = (const float*)d_in[7];
    const float* erev     = (const float*)d_in[8];
    const float* ssig     = (const float*)d_in[9];
    const float* smu      = (const float*)d_in[10];
    const float* sw       = (const float*)d_in[11];
    const float* serev    = (const float*)d_in[12];
    const float* input_w  = (const float*)d_in[13];
    const float* input_b  = (const float*)d_in[14];
    const float* output_w = (const float*)d_in[15];
    const float* output_b = (const float*)d_in[16];
    const float* mask     = (const float*)d_in[17];
    const float* smask    = (const float*)d_in[18];

    float* out = (float*)d_out;
    float* ws  = (float*)d_ws;

    float4* pw4 = (float4*)ws;                 // U*U float4 (4 MB)
    float*  wns = ws + 4 * UNITS * UNITS;      // B*U
    float*  wds = wns + BATCH * UNITS;         // B*U
    float*  stA = wds + BATCH * UNITS;         // B*U
    float*  stB = stA + BATCH * UNITS;         // B*U

    prep_kernel<<<1024, 256, 0, stream>>>(
        inputs, sigma, mu, w, erev, mask,
        ssig, smu, sw, serev, smask, input_w, input_b,
        pw4, wns, wds);

    float* state_out = out + BATCH * MOTOR;
    float* dsts[UNFOLDS] = {stA, stB, stA, stB, stA, state_out};
    const float* src = state;
    for (int t = 0; t < UNFOLDS; ++t) {
        int last = (t == UNFOLDS - 1) ? 1 : 0;
        unfold_kernel<<<1024, THR, 0, stream>>>(
            src, dsts[t], pw4, wns, wds,
            gleak, vleak, cm, output_w, output_b, out, last);
        src = dsts[t];
    }
}